// Round 1
// baseline (541.145 us; speedup 1.0000x reference)
//
#include <hip/hip_runtime.h>

#define NNODES 16384
#define K 32
#define S 16
#define D 190
#define E 64
#define NREL 3

__global__ __launch_bounds__(256) void interagg_fused(
    const float* __restrict__ features,   // [N_TOTAL, D]
    const int*   __restrict__ nodes,      // [N]
    const int*   __restrict__ neigh1,     // [N, K]
    const int*   __restrict__ neigh2,
    const int*   __restrict__ neigh3,
    const float* __restrict__ weight,     // [D, E]
    const float* __restrict__ avec,       // [2E]
    float*       __restrict__ out)        // [N, E]
{
    __shared__ float s_center[D];
    __shared__ float s_rmean[NREL][D];
    __shared__ float s_sim[NREL][K];
    __shared__ int   s_idx[NREL][K];
    __shared__ unsigned char s_sel[NREL][K];
    __shared__ float s_h[4][E];           // [0]=center_h, [1..3]=neigh_h
    __shared__ float s_dots[4];

    const int n    = blockIdx.x;
    const int t    = threadIdx.x;
    const int lane = t & 63;
    const int wave = t >> 6;

    // ---- phase 1: load center row + neighbor indices ----
    const int crow = nodes[n];
    if (t < D) s_center[t] = features[(size_t)crow * D + t];
    if (t < K) {
        s_idx[0][t] = neigh1[n * K + t];
        s_idx[1][t] = neigh2[n * K + t];
        s_idx[2][t] = neigh3[n * K + t];
    }
    __syncthreads();

    // ---- phase 2: cosine sims (96 rows; wave w handles 24 rows) ----
    // sim ranking is invariant to the positive constant 1/||center||, so
    // we rank by dot / ||nf|| only. sqrtf+div are monotone correctly-rounded,
    // so float ties match the reference's tie set (dup indices -> same row).
    for (int p = wave * 24; p < wave * 24 + 24; ++p) {
        const int r = p >> 5;
        const int k = p & (K - 1);
        const float* __restrict__ row = features + (size_t)s_idx[r][k] * D;
        float dot = 0.f, ss = 0.f;
        for (int d = lane; d < D; d += 64) {
            const float v = row[d];
            dot = fmaf(s_center[d], v, dot);
            ss  = fmaf(v, v, ss);
        }
        for (int off = 32; off; off >>= 1) {
            dot += __shfl_xor(dot, off, 64);
            ss  += __shfl_xor(ss,  off, 64);
        }
        if (lane == 0) s_sim[r][k] = dot / sqrtf(ss);
    }
    __syncthreads();

    // ---- phase 3a: top-S selection by rank (ties -> lower index, as lax.top_k) ----
    if (t < NREL * K) {
        const int r = t >> 5, k = t & (K - 1);
        const float sk = s_sim[r][k];
        int rank = 0;
        #pragma unroll
        for (int j = 0; j < K; ++j) {
            const float sj = s_sim[r][j];
            rank += (sj > sk) || (sj == sk && j < k);
        }
        s_sel[r][k] = (rank < S) ? 1 : 0;
    }
    __syncthreads();

    // ---- phase 3b: masked mean + relu (lane-per-dim, coalesced row reads) ----
    if (t < D) {
        #pragma unroll
        for (int r = 0; r < NREL; ++r) {
            float acc = 0.f;
            for (int k = 0; k < K; ++k) {
                if (s_sel[r][k])   // uniform across lanes -> no divergence
                    acc += features[(size_t)s_idx[r][k] * D + t];
            }
            s_rmean[r][t] = fmaxf(acc * (1.f / S), 0.f);
        }
    }
    __syncthreads();

    // ---- phase 4: h[v] = vec_v @ W  (v: 0=center, 1..3=relations) ----
    {
        const float* vec = (wave == 0) ? s_center : s_rmean[wave - 1];
        float acc = 0.f;
        #pragma unroll 5
        for (int d = 0; d < D; ++d)
            acc = fmaf(vec[d], weight[d * E + lane], acc);
        s_h[wave][lane] = acc;
    }
    __syncthreads();

    // ---- phase 5: attention dots (wave w: dot(s_h[w], w==0 ? a1 : a2)) ----
    {
        const float* av = (wave == 0) ? avec : (avec + E);
        float val = s_h[wave][lane] * av[lane];
        for (int off = 32; off; off >>= 1)
            val += __shfl_xor(val, off, 64);
        if (lane == 0) s_dots[wave] = val;
    }
    __syncthreads();

    // ---- phase 6: leaky-relu, 3-way softmax, aggregate, relu, store ----
    if (t < E) {
        const float d0 = s_dots[0];
        float e1 = d0 + s_dots[1];
        float e2 = d0 + s_dots[2];
        float e3 = d0 + s_dots[3];
        e1 = (e1 >= 0.f) ? e1 : 0.2f * e1;
        e2 = (e2 >= 0.f) ? e2 : 0.2f * e2;
        e3 = (e3 >= 0.f) ? e3 : 0.2f * e3;
        const float m  = fmaxf(e1, fmaxf(e2, e3));
        const float x1 = expf(e1 - m), x2 = expf(e2 - m), x3 = expf(e3 - m);
        const float inv = 1.f / (x1 + x2 + x3);
        const float agg = (x1 * s_h[1][t] + x2 * s_h[2][t] + x3 * s_h[3][t]) * inv;
        out[(size_t)n * E + t] = fmaxf(s_h[0][t] + agg, 0.f);
    }
}

extern "C" void kernel_launch(void* const* d_in, const int* in_sizes, int n_in,
                              void* d_out, int out_size, void* d_ws, size_t ws_size,
                              hipStream_t stream) {
    const float* features = (const float*)d_in[0];
    const int*   nodes    = (const int*)  d_in[1];
    const int*   neigh1   = (const int*)  d_in[2];
    const int*   neigh2   = (const int*)  d_in[3];
    const int*   neigh3   = (const int*)  d_in[4];
    const float* weight   = (const float*)d_in[5];
    const float* avec     = (const float*)d_in[6];
    float*       out      = (float*)d_out;

    interagg_fused<<<NNODES, 256, 0, stream>>>(
        features, nodes, neigh1, neigh2, neigh3, weight, avec, out);
}

// Round 2
// 446.535 us; speedup vs baseline: 1.2119x; 1.2119x over previous
//
#include <hip/hip_runtime.h>

#define NTOTAL 100000
#define NNODES 16384
#define K 32
#define S 16
#define D 190
#define E 64
#define NREL 3
#define D2 95   // float2 elements per feature row (190*4B = 760B, 8B-aligned)

// ---------- helper: inverse L2 norms of all feature rows ----------
__global__ __launch_bounds__(256) void norms_kernel(const float* __restrict__ features,
                                                    float* __restrict__ invn) {
    const int row  = blockIdx.x * 4 + (threadIdx.x >> 6);
    const int lane = threadIdx.x & 63;
    if (row >= NTOTAL) return;
    const float2* rp = (const float2*)(features + (size_t)row * D);
    float2 a = rp[lane];
    float ss = fmaf(a.x, a.x, a.y * a.y);
    if (lane < D2 - 64) {
        float2 b = rp[64 + lane];
        ss = fmaf(b.x, b.x, fmaf(b.y, b.y, ss));
    }
    #pragma unroll
    for (int off = 32; off; off >>= 1) ss += __shfl_xor(ss, off, 64);
    if (lane == 0) invn[row] = 1.0f / sqrtf(ss);
}

// ---------- fused main kernel: one block per node ----------
template <bool HAVE_NORMS>
__global__ __launch_bounds__(256) void interagg_fused(
    const float* __restrict__ features,   // [N_TOTAL, D]
    const int*   __restrict__ nodes,      // [N]
    const int*   __restrict__ neigh1,     // [N, K]
    const int*   __restrict__ neigh2,
    const int*   __restrict__ neigh3,
    const float* __restrict__ weight,     // [D, E]
    const float* __restrict__ avec,       // [2E]
    const float* __restrict__ invn,       // [N_TOTAL] or nullptr
    float*       __restrict__ out)        // [N, E]
{
    __shared__ __align__(16) float s_center[D];
    __shared__ float s_rmean[NREL][D];
    __shared__ float s_sim[NREL][K];
    __shared__ int   s_idx[NREL][K];
    __shared__ int   s_selidx[NREL][S];
    __shared__ float s_h[4][E];           // [0]=center_h, [1..3]=neigh_h
    __shared__ float s_dots[4];

    const int n    = blockIdx.x;
    const int t    = threadIdx.x;
    const int lane = t & 63;
    const int wave = t >> 6;

    // ---- phase 1: neighbor indices -> LDS; center row -> registers ----
    const int crow = nodes[n];
    if (t < K) {
        s_idx[0][t] = neigh1[n * K + t];
        s_idx[1][t] = neigh2[n * K + t];
        s_idx[2][t] = neigh3[n * K + t];
    }
    const float2* crp = (const float2*)(features + (size_t)crow * D);
    float2 c0 = crp[lane];                       // d2 = 0..63
    float2 c1 = make_float2(0.f, 0.f);
    if (lane < D2 - 64) c1 = crp[64 + lane];     // d2 = 64..94
    if (wave == 0) {
        ((float2*)s_center)[lane] = c0;
        if (lane < D2 - 64) ((float2*)s_center)[64 + lane] = c1;
    }
    __syncthreads();

    // ---- phase 2: 96 cosine sims; wave handles 24 rows in 4 groups of 6 ----
    // Ranking is invariant to the positive factor 1/||center||; rank by dot*invnorm.
    {
        const int pbase = wave * 24;
        #pragma unroll
        for (int g = 0; g < 4; ++g) {
            const float2* rp[6];
            float inv6[6];
            int rr[6], kk[6];
            #pragma unroll
            for (int i = 0; i < 6; ++i) {
                const int p = pbase + g * 6 + i;
                rr[i] = p >> 5;
                kk[i] = p & (K - 1);
                const int ridx = s_idx[rr[i]][kk[i]];
                rp[i] = (const float2*)(features + (size_t)ridx * D);
                if (HAVE_NORMS) inv6[i] = invn[ridx];   // uniform addr -> broadcast
            }
            // batch-issue 12 independent gather loads (high MLP)
            float2 va[6], vb[6];
            #pragma unroll
            for (int i = 0; i < 6; ++i) {
                va[i] = rp[i][lane];
                vb[i] = make_float2(0.f, 0.f);
                if (lane < D2 - 64) vb[i] = rp[i][64 + lane];
            }
            float dot[6], ssv[6];
            #pragma unroll
            for (int i = 0; i < 6; ++i) {
                dot[i] = fmaf(c0.x, va[i].x, fmaf(c0.y, va[i].y,
                         fmaf(c1.x, vb[i].x, c1.y * vb[i].y)));
                if (!HAVE_NORMS)
                    ssv[i] = fmaf(va[i].x, va[i].x, fmaf(va[i].y, va[i].y,
                             fmaf(vb[i].x, vb[i].x, vb[i].y * vb[i].y)));
            }
            // 6 independent butterfly reductions (ILP hides shuffle latency)
            #pragma unroll
            for (int i = 0; i < 6; ++i) {
                float v = dot[i];
                #pragma unroll
                for (int off = 32; off; off >>= 1) v += __shfl_xor(v, off, 64);
                if (HAVE_NORMS) {
                    if (lane == 0) s_sim[rr[i]][kk[i]] = v * inv6[i];
                } else {
                    float s2 = ssv[i];
                    #pragma unroll
                    for (int off = 32; off; off >>= 1) s2 += __shfl_xor(s2, off, 64);
                    if (lane == 0) s_sim[rr[i]][kk[i]] = v / sqrtf(s2);
                }
            }
        }
    }
    __syncthreads();

    // ---- phase 3a: top-S by rank (ties -> lower index, matches lax.top_k);
    //      rank is unique per selected element -> compact index list ----
    if (t < NREL * K) {
        const int r = t >> 5, k = t & (K - 1);
        const float sk = s_sim[r][k];
        int rank = 0;
        #pragma unroll
        for (int j = 0; j < K; ++j) {
            const float sj = s_sim[r][j];
            rank += (sj > sk) || (sj == sk && j < k);
        }
        if (rank < S) s_selidx[r][rank] = s_idx[r][k];
    }
    __syncthreads();

    // ---- phase 3b: masked mean + relu (lane-per-dim, 16 branch-free loads) ----
    if (t < D) {
        #pragma unroll
        for (int r = 0; r < NREL; ++r) {
            float acc = 0.f;
            #pragma unroll
            for (int j = 0; j < S; ++j)
                acc += features[(size_t)s_selidx[r][j] * D + t];
            s_rmean[r][t] = fmaxf(acc * (1.f / S), 0.f);
        }
    }
    __syncthreads();

    // ---- phase 4: h[v] = vec_v @ W ----
    {
        const float* vec = (wave == 0) ? s_center : s_rmean[wave - 1];
        float acc = 0.f;
        #pragma unroll 5
        for (int d = 0; d < D; ++d)
            acc = fmaf(vec[d], weight[d * E + lane], acc);
        s_h[wave][lane] = acc;
    }
    __syncthreads();

    // ---- phase 5: attention dots ----
    {
        const float* av = (wave == 0) ? avec : (avec + E);
        float val = s_h[wave][lane] * av[lane];
        #pragma unroll
        for (int off = 32; off; off >>= 1) val += __shfl_xor(val, off, 64);
        if (lane == 0) s_dots[wave] = val;
    }
    __syncthreads();

    // ---- phase 6: leaky-relu, 3-way softmax, aggregate, relu, store ----
    if (t < E) {
        const float d0 = s_dots[0];
        float e1 = d0 + s_dots[1];
        float e2 = d0 + s_dots[2];
        float e3 = d0 + s_dots[3];
        e1 = (e1 >= 0.f) ? e1 : 0.2f * e1;
        e2 = (e2 >= 0.f) ? e2 : 0.2f * e2;
        e3 = (e3 >= 0.f) ? e3 : 0.2f * e3;
        const float m  = fmaxf(e1, fmaxf(e2, e3));
        const float x1 = expf(e1 - m), x2 = expf(e2 - m), x3 = expf(e3 - m);
        const float inv = 1.f / (x1 + x2 + x3);
        const float agg = (x1 * s_h[1][t] + x2 * s_h[2][t] + x3 * s_h[3][t]) * inv;
        out[(size_t)n * E + t] = fmaxf(s_h[0][t] + agg, 0.f);
    }
}

extern "C" void kernel_launch(void* const* d_in, const int* in_sizes, int n_in,
                              void* d_out, int out_size, void* d_ws, size_t ws_size,
                              hipStream_t stream) {
    const float* features = (const float*)d_in[0];
    const int*   nodes    = (const int*)  d_in[1];
    const int*   neigh1   = (const int*)  d_in[2];
    const int*   neigh2   = (const int*)  d_in[3];
    const int*   neigh3   = (const int*)  d_in[4];
    const float* weight   = (const float*)d_in[5];
    const float* avec     = (const float*)d_in[6];
    float*       out      = (float*)d_out;

    const bool have_norms = ws_size >= (size_t)NTOTAL * sizeof(float);
    if (have_norms) {
        float* invn = (float*)d_ws;
        norms_kernel<<<(NTOTAL + 3) / 4, 256, 0, stream>>>(features, invn);
        interagg_fused<true><<<NNODES, 256, 0, stream>>>(
            features, nodes, neigh1, neigh2, neigh3, weight, avec, invn, out);
    } else {
        interagg_fused<false><<<NNODES, 256, 0, stream>>>(
            features, nodes, neigh1, neigh2, neigh3, weight, avec, nullptr, out);
    }
}